// Round 9
// baseline (130.509 us; speedup 1.0000x reference)
//
#include <hip/hip_runtime.h>

// Bidirectional LSTM, B=16384 T=512 I=1 H=8, + final linear on [h_f(T-1), h_b(T-1)].
// Backward direction's state at time T-1 is its FIRST scan step -> one step only.
//
// R9: 4 lanes per element (each lane owns cells 2*j2 and 2*j2+1, computes all
// 8 of their gate rows). Why:
//  - h-broadcast is now entirely quad-local: 8 quad_perm DPP movs deliver all
//    8 h values in natural order (elements are quad-aligned). ZERO ds_swizzle
//    -> the ~90 cyc/step lgkmcnt exposure of the 8-lane layout is gone.
//  - trans per element drops 16 -> 15 per 2 cells (cell-tanh rcp paired across
//    the lane's two cells).
//  - issue per 16 elements: ~468 cyc (1 wave) vs ~590 (2 waves, 8-lane layout).
//  - dot products have 8 independent FMA chains -> enough ILP for 1 wave/SIMD.
// Kept from R8: activation scales folded into weights (i,f,o rows x -log2e,
// g rows x +2log2e), paired reciprocals, cell state pre-scaled by 2log2e,
// software-pipelined unconditional x prefetch (no conditional select -> no
// scratch spill), scalar fma compiler-scheduled.

#define LOG2E 1.4426950408889634f

// quad_perm broadcast lane k within each 4-lane quad (k = 0..3): ctrl = k * 0x55
#define DPPQ(v, k) __int_as_float(__builtin_amdgcn_update_dpp(0, __float_as_int(v), ((k) * 0x55), 0xF, 0xF, true))

struct Ctx4 {
    // row order r = gate*2 + cell: i0,i1,f0,f1,g0,g1,o0,o1 (cells 2*j2, 2*j2+1)
    float w[8][8];    // recurrent rows, pre-scaled
    float wx[8];      // input weights, pre-scaled
    float bb[8];      // biases, pre-scaled
};

__device__ __forceinline__ void load_ctx4(Ctx4& C, int j2,
    const float* __restrict__ w_ih, const float* __restrict__ w_hh,
    const float* __restrict__ b)
{
#pragma unroll
    for (int r = 0; r < 8; ++r) {
        int gate = r >> 1;            // 0=i,1=f,2=g,3=o
        int cell = r & 1;
        int row = gate * 8 + 2 * j2 + cell;
        float s = (gate == 2) ? (2.0f * LOG2E) : (-LOG2E);
        const float4* wr = (const float4*)(w_hh + (size_t)row * 8);
        float4 a = wr[0], q = wr[1];
        C.w[r][0] = a.x * s; C.w[r][1] = a.y * s;
        C.w[r][2] = a.z * s; C.w[r][3] = a.w * s;
        C.w[r][4] = q.x * s; C.w[r][5] = q.y * s;
        C.w[r][6] = q.z * s; C.w[r][7] = q.w * s;
        C.wx[r] = w_ih[row] * s;
        C.bb[r] = b[row] * s;
    }
}

// csA/csB are the two cell states pre-scaled by 2*log2(e).
__device__ __forceinline__ void lstm_step4(float xt, float& hA, float& hB,
                                           float& csA, float& csB, const Ctx4& C)
{
    // all-quad broadcast: hk[2k+d] = cell (2k+d)'s h, natural order
    float hk0 = DPPQ(hA, 0), hk1 = DPPQ(hB, 0);
    float hk2 = DPPQ(hA, 1), hk3 = DPPQ(hB, 1);
    float hk4 = DPPQ(hA, 2), hk5 = DPPQ(hB, 2);
    float hk6 = DPPQ(hA, 3), hk7 = DPPQ(hB, 3);

    float z[8];
#pragma unroll
    for (int r = 0; r < 8; ++r) z[r] = fmaf(xt, C.wx[r], C.bb[r]);
#pragma unroll
    for (int r = 0; r < 8; ++r) {
        z[r] = fmaf(hk0, C.w[r][0], z[r]);
        z[r] = fmaf(hk1, C.w[r][1], z[r]);
        z[r] = fmaf(hk2, C.w[r][2], z[r]);
        z[r] = fmaf(hk3, C.w[r][3], z[r]);
        z[r] = fmaf(hk4, C.w[r][4], z[r]);
        z[r] = fmaf(hk5, C.w[r][5], z[r]);
        z[r] = fmaf(hk6, C.w[r][6], z[r]);
        z[r] = fmaf(hk7, C.w[r][7], z[r]);
    }

    // e = exp2(z'): rows i,f,o give e^{-z}; rows g give e^{2z}
    float e0 = __builtin_amdgcn_exp2f(z[0]);
    float e1 = __builtin_amdgcn_exp2f(z[1]);
    float e2 = __builtin_amdgcn_exp2f(z[2]);
    float e3 = __builtin_amdgcn_exp2f(z[3]);
    float e4 = __builtin_amdgcn_exp2f(z[4]);
    float e5 = __builtin_amdgcn_exp2f(z[5]);
    float e6 = __builtin_amdgcn_exp2f(z[6]);
    float e7 = __builtin_amdgcn_exp2f(z[7]);
    float di0 = 1.0f + e0, di1 = 1.0f + e1;
    float df0 = 1.0f + e2, df1 = 1.0f + e3;
    float dg0 = 1.0f + e4, dg1 = 1.0f + e5;
    float do0 = 1.0f + e6, do1 = 1.0f + e7;

    // paired reciprocals: (i,f) per cell, (g,o) per cell -> 4 rcp for 8 gates
    float Ra0 = __builtin_amdgcn_rcpf(di0 * df0);
    float sigi0 = Ra0 * df0, sigf0 = Ra0 * di0;
    float Ra1 = __builtin_amdgcn_rcpf(di1 * df1);
    float sigi1 = Ra1 * df1, sigf1 = Ra1 * di1;
    float Rb0 = __builtin_amdgcn_rcpf(dg0 * do0);
    float qg0 = Rb0 * do0, sigo0 = Rb0 * dg0;
    float Rb1 = __builtin_amdgcn_rcpf(dg1 * do1);
    float qg1 = Rb1 * do1, sigo1 = Rb1 * dg1;

    // tgs = 2*log2(e)*tanh(g)
    float tgs0 = fmaf(-4.0f * LOG2E, qg0, 2.0f * LOG2E);
    float tgs1 = fmaf(-4.0f * LOG2E, qg1, 2.0f * LOG2E);
    csA = fmaf(sigf0, csA, sigi0 * tgs0);
    csB = fmaf(sigf1, csB, sigi1 * tgs1);

    // tanh(c) = 1 - 2/(1+e^{2c}); e^{2c} = exp2(cs). Cell rcp paired across cells.
    float ecA = __builtin_amdgcn_exp2f(csA);
    float ecB = __builtin_amdgcn_exp2f(csB);
    float dcA = 1.0f + ecA, dcB = 1.0f + ecB;
    float Rc = __builtin_amdgcn_rcpf(dcA * dcB);
    float qcA = Rc * dcB, qcB = Rc * dcA;
    hA = sigo0 * fmaf(-2.0f, qcA, 1.0f);
    hB = sigo1 * fmaf(-2.0f, qcB, 1.0f);
}

__global__ __launch_bounds__(256, 1) void bilstm_kernel(
    const float* __restrict__ x, const float* __restrict__ h0, const float* __restrict__ c0,
    const float* __restrict__ w_ih_f, const float* __restrict__ w_hh_f, const float* __restrict__ b_f,
    const float* __restrict__ w_ih_b, const float* __restrict__ w_hh_b, const float* __restrict__ b_b,
    const float* __restrict__ w_lin, const float* __restrict__ b_lin,
    float* __restrict__ out, int B, int T)
{
    int tid = blockIdx.x * 256 + threadIdx.x;
    int b = tid >> 2;
    int j2 = tid & 3;                 // this lane owns cells 2*j2, 2*j2+1
    if (b >= B) return;

    Ctx4 Cf;
    load_ctx4(Cf, j2, w_ih_f, w_hh_f, b_f);

    float hA  = h0[(size_t)b * 8 + 2 * j2];
    float hB  = h0[(size_t)b * 8 + 2 * j2 + 1];
    float csA = c0[(size_t)b * 8 + 2 * j2] * (2.0f * LOG2E);
    float csB = c0[(size_t)b * 8 + 2 * j2 + 1] * (2.0f * LOG2E);

    const float4* xr = (const float4*)(x + (size_t)b * T);
    int nT4 = T >> 2;
    float4 xv = xr[0];
    // software pipeline: load group t4+1 unconditionally, use group t4
    for (int t4 = 0; t4 < nT4 - 1; ++t4) {
        float4 nxt = xr[t4 + 1];
        lstm_step4(xv.x, hA, hB, csA, csB, Cf);
        lstm_step4(xv.y, hA, hB, csA, csB, Cf);
        lstm_step4(xv.z, hA, hB, csA, csB, Cf);
        lstm_step4(xv.w, hA, hB, csA, csB, Cf);
        xv = nxt;
    }
    // epilogue: last group
    lstm_step4(xv.x, hA, hB, csA, csB, Cf);
    lstm_step4(xv.y, hA, hB, csA, csB, Cf);
    lstm_step4(xv.z, hA, hB, csA, csB, Cf);
    float xlast = xv.w;
    lstm_step4(xlast, hA, hB, csA, csB, Cf);

    // backward direction: exactly one step on x[:, T-1] (== xv.w)
    Ctx4 Cb;
    load_ctx4(Cb, j2, w_ih_b, w_hh_b, b_b);
    float hbA  = h0[(size_t)B * 8 + (size_t)b * 8 + 2 * j2];
    float hbB  = h0[(size_t)B * 8 + (size_t)b * 8 + 2 * j2 + 1];
    float cbA  = c0[(size_t)B * 8 + (size_t)b * 8 + 2 * j2] * (2.0f * LOG2E);
    float cbB  = c0[(size_t)B * 8 + (size_t)b * 8 + 2 * j2 + 1] * (2.0f * LOG2E);
    lstm_step4(xlast, hbA, hbB, cbA, cbB, Cb);

    // final linear: out[b] = sum over 16 terms + b_lin, reduced across the quad
    float part = fmaf(hA, w_lin[2 * j2],
                 fmaf(hB, w_lin[2 * j2 + 1],
                 fmaf(hbA, w_lin[8 + 2 * j2], hbB * w_lin[8 + 2 * j2 + 1])));
    part += __shfl_xor(part, 1, 4);
    part += __shfl_xor(part, 2, 4);
    if (j2 == 0) out[b] = part + b_lin[0];
}

extern "C" void kernel_launch(void* const* d_in, const int* in_sizes, int n_in,
                              void* d_out, int out_size, void* d_ws, size_t ws_size,
                              hipStream_t stream)
{
    const float* x      = (const float*)d_in[0];
    const float* h0     = (const float*)d_in[1];
    const float* c0     = (const float*)d_in[2];
    const float* w_ih_f = (const float*)d_in[3];
    const float* w_hh_f = (const float*)d_in[4];
    const float* b_f    = (const float*)d_in[5];
    const float* w_ih_b = (const float*)d_in[6];
    const float* w_hh_b = (const float*)d_in[7];
    const float* b_b    = (const float*)d_in[8];
    const float* w_lin  = (const float*)d_in[9];
    const float* b_lin  = (const float*)d_in[10];
    float* out = (float*)d_out;

    int B = in_sizes[1] / 16;   // h0: (2, B, 8)
    int T = in_sizes[0] / B;    // x:  (B, T, 1)

    int threads = B * 4;
    dim3 block(256);
    dim3 grid((threads + 255) / 256);
    hipLaunchKernelGGL(bilstm_kernel, grid, block, 0, stream,
                       x, h0, c0, w_ih_f, w_hh_f, b_f, w_ih_b, w_hh_b, b_b,
                       w_lin, b_lin, out, B, T);
}